// Round 11
// baseline (161.075 us; speedup 1.0000x reference)
//
#include <hip/hip_runtime.h>
#include <hip/hip_bf16.h>
#include <stdint.h>
#include <stddef.h>

typedef float  f32x4  __attribute__((ext_vector_type(4)));
typedef float  f32x16 __attribute__((ext_vector_type(16)));
typedef int    i32x8  __attribute__((ext_vector_type(8)));
typedef unsigned char u8;

#define LOG2E  1.44269504f
#define QSCALE 0.18033688f      /* 0.125 * log2(e) */
#define WSC    16.0f            /* weight prescale before fp8 cast */
#define IWSC   0.0625f
#define QSTORE 0.36067376f      /* QSCALE * 32 / 16 : gemm-acc -> q_fp8 */
#define KSTORE 0.5f             /* 8 / 16          : gemm-acc -> k_fp8 */
#define SCALE_A_M8 0x77777777   /* e8m0 119 = 2^-8 (undo 32*8) */
#define SCALE_ONE  0x7F7F7F7F   /* e8m0 127 = 1.0 */

// ---------------------------------------------------------------- helpers
__device__ __forceinline__ void gld_lds16(const void* gptr, void* lptr) {
    __builtin_amdgcn_global_load_lds(
        (const __attribute__((address_space(1))) unsigned int*)gptr,
        (__attribute__((address_space(3))) unsigned int*)lptr,
        16, 0, 0);
}

// ---------------------------------------------------------------- merged cast + zero
// fp8 e4m3. blocks [0,6144): g (x1) ; [6144,6720): wq ; [6720,7296): wk ;
// [7296,9600): w_hn (weights x16). blocks [0,104) zero sums; block 0 zeroes out[0].
__global__ void cast_all(const float* __restrict__ g, const float* __restrict__ wq,
                         const float* __restrict__ wk, const float* __restrict__ whn,
                         u8* __restrict__ g_f8, u8* __restrict__ Wcat,
                         float* __restrict__ sums, float* __restrict__ out) {
    int b = blockIdx.x, t = threadIdx.x;
    if (b < 104) {
        float4 z = {0.f, 0.f, 0.f, 0.f};
        *(float4*)(sums + (b * 256 + t) * 4) = z;
        if (b == 0 && t == 0) out[0] = 0.f;
    }
    const float* src; u8* dst; int off; float sc;
    if (b < 6144)      { src = g;   dst = g_f8;           off = 0;    sc = 1.0f; }
    else if (b < 6720) { src = wq;  dst = Wcat;           off = 6144; sc = WSC;  }
    else if (b < 7296) { src = wk;  dst = Wcat + 589824;  off = 6720; sc = WSC;  }
    else               { src = whn; dst = Wcat + 1179648; off = 7296; sc = WSC;  }
    int i = ((b - off) * 256 + t) * 4;
    float4 v = *(const float4*)(src + i);
    int p = __builtin_amdgcn_cvt_pk_fp8_f32(sc * v.x, sc * v.y, 0, false);
    p     = __builtin_amdgcn_cvt_pk_fp8_f32(sc * v.z, sc * v.w, p, true);
    *(int*)(dst + i) = p;
}

// ---------------------------------------------------------------- fused NT GEMM (MX-fp8)
// C_full[M,4608] = A[M,768] * Wcat[4608,768]^T, fp8 e4m3, fp32 acc.
// R11: mfma_scale_f32_32x32x64_f8f6f4, BK=64, DOUBLE-BUFFERED (2 x 8KB per matrix,
// 32 KB total = same footprint as R10 -> occupancy preserved) with ONE barrier per
// K-iter; the vmcnt drain covers loads issued a full iteration earlier (cheap).
// LDS layout: attn-verified super-row swizzle — 2 rows per 128 B super-row u,
// slot sigma holds (row = 2u + (s'>>2), kseg16 = s'&3) where s' = sigma^(u&7).
// Staged via swizzled global source (line-count identical to linear; L2-resident).
// A and B share the load pattern -> any shared k-relabel cancels in A*B^T.
// cols [0,1536): q/k -> fp8 qkh planes (super-row swizzled), q*QSTORE, k*KSTORE.
// cols [1536,4608): Hopfield -> rowsum += exp2(beta*log2e/16 * acc) via atomicAdd.
__global__ void gemm_fused(const u8* __restrict__ A, const u8* __restrict__ Bm,
                           u8* __restrict__ qkh, float* __restrict__ rowsum,
                           const float* __restrict__ beta_p) {
    __shared__ __align__(16) u8 As[2][8192];
    __shared__ __align__(16) u8 Bs[2][8192];
    const int t = threadIdx.x;
    const int w = t >> 6, l = t & 63;
    const int wm = (w >> 1) * 64, wn = (w & 1) * 64;
    const int tile_m = blockIdx.x * 128;
    const int tile_n = blockIdx.y * 128;

    f32x16 acc[2][2];
#pragma unroll
    for (int i = 0; i < 2; i++)
#pragma unroll
        for (int j = 0; j < 2; j++)
#pragma unroll
            for (int q = 0; q < 16; q++) acc[i][j][q] = 0.f;

    // staging map: LDS slot (i*256+t)*16 -> super-row u=(i*256+t)>>3, sigma=t&7;
    // s' = sigma^(u&7) -> global row 2u+(s'>>2), kseg s'&3  (k0 added per iter)
    const u8* gA[2]; const u8* gB[2];
#pragma unroll
    for (int i = 0; i < 2; i++) {
        int sl = i * 256 + t, u = sl >> 3;
        int su = (t & 7) ^ (u & 7);
        int row = 2 * u + (su >> 2), ks = su & 3;
        gA[i] = A  + (size_t)(tile_m + row) * 768 + ks * 16;
        gB[i] = Bm + (size_t)(tile_n + row) * 768 + ks * 16;
    }

    const int ln = l & 31, lh = l >> 5;
    const int sb = (ln & 1) * 4 + lh * 2;   // fragment base slot (c in {0,1})
    union F8x32 { uint4 q[2]; i32x8 v; };

    // prologue: stage k=0 into buf 0
#pragma unroll
    for (int i = 0; i < 2; i++) {
        gld_lds16(gA[i], As[0] + (i * 256 + t) * 16);
        gld_lds16(gB[i], Bs[0] + (i * 256 + t) * 16);
    }

#pragma unroll
    for (int kk = 0; kk < 12; kk++) {
        const int p = kk & 1;
        __builtin_amdgcn_s_waitcnt(0);   // my stage(kk) landed (issued 1 iter ago)
        __syncthreads();                 // everyone's landed; everyone past compute(kk-1)
        if (kk < 11) {
#pragma unroll
            for (int i = 0; i < 2; i++) {
                gld_lds16(gA[i] + (kk + 1) * 64, As[p ^ 1] + (i * 256 + t) * 16);
                gld_lds16(gB[i] + (kk + 1) * 64, Bs[p ^ 1] + (i * 256 + t) * 16);
            }
        }
        i32x8 af[2], bf[2];
#pragma unroll
        for (int mi = 0; mi < 2; mi++) {
            int rA = wm + mi * 32 + ln, uA = rA >> 1, u7 = uA & 7;
            F8x32 x;
            x.q[0] = *(const uint4*)(As[p] + uA * 128 + ((sb)     ^ u7) * 16);
            x.q[1] = *(const uint4*)(As[p] + uA * 128 + ((sb + 1) ^ u7) * 16);
            af[mi] = x.v;
            int rB = wn + mi * 32 + ln, uB = rB >> 1, v7 = uB & 7;
            F8x32 y;
            y.q[0] = *(const uint4*)(Bs[p] + uB * 128 + ((sb)     ^ v7) * 16);
            y.q[1] = *(const uint4*)(Bs[p] + uB * 128 + ((sb + 1) ^ v7) * 16);
            bf[mi] = y.v;
        }
#pragma unroll
        for (int mi = 0; mi < 2; mi++)
#pragma unroll
            for (int nj = 0; nj < 2; nj++)
                acc[mi][nj] = __builtin_amdgcn_mfma_scale_f32_32x32x64_f8f6f4(
                    af[mi], bf[nj], acc[mi][nj], 0, 0, 0, SCALE_ONE, 0, SCALE_ONE);
    }

    // C/D layout (32x32, m74/m101-verified): col=lane&31, row=(r&3)+8*(r>>2)+4*lh
    if (tile_n < 1536) {
        const int tt = (tile_n >= 768);
        const int bb = tile_m >> 10;
        const int m7 = tile_m & 1023;
        const float sc = tt ? KSTORE : QSTORE;
#pragma unroll
        for (int mi = 0; mi < 2; mi++)
#pragma unroll
            for (int nj = 0; nj < 2; nj++) {
                const int colbase = tile_n - tt * 768 + wn + nj * 32;  // 0..767
                const int hh = colbase >> 6;
                const int z  = (colbase & 63) + ln;                    // 0..63
                u8* base = qkh + ((size_t)((bb * 12 + hh) * 2 + tt) << 16);
#pragma unroll
                for (int r = 0; r < 16; r++) {
                    int kr = m7 + wm + mi * 32 + (r & 3) + 8 * (r >> 2) + 4 * lh;
                    int u = kr >> 1, u7 = u & 7;
                    int slot = ((kr & 1) * 4 + (z >> 4)) ^ u7;
                    int pv = __builtin_amdgcn_cvt_pk_fp8_f32(sc * acc[mi][nj][r], 0.f, 0, false);
                    base[(size_t)u * 128 + slot * 16 + (z & 15)] = (u8)(pv & 0xFF);
                }
            }
    } else {
        const float sc2 = beta_p[0] * LOG2E * IWSC;
#pragma unroll
        for (int mi = 0; mi < 2; mi++)
#pragma unroll
            for (int r = 0; r < 16; r++) {
                float s = __builtin_amdgcn_exp2f(sc2 * acc[mi][0][r])
                        + __builtin_amdgcn_exp2f(sc2 * acc[mi][1][r]);
                s += __shfl_xor(s, 1, 32);
                s += __shfl_xor(s, 2, 32);
                s += __shfl_xor(s, 4, 32);
                s += __shfl_xor(s, 8, 32);
                s += __shfl_xor(s, 16, 32);
                if (ln == 0)
                    atomicAdd(&rowsum[tile_m + wm + mi * 32 + (r & 3) + 8 * (r >> 2) + 4 * lh], s);
            }
    }
}

// ---------------------------------------------------------------- attention exp-sums
// qkh fp8 planes (super-row swizzled). grid (qt*2+kh:16, h:12, b:8), 256 thr.
// All 512 K-rows staged once (32 KB LDS, one drain+barrier); Q frags direct
// global->VGPR; mfma_scale_f32_32x32x64_f8f6f4 with scale_a = 2^-8 folding all
// gains: acc = beta*log2e*(q.k) -> rs += exp2(acc).
__global__ void __launch_bounds__(256, 4)
attn_energy(const u8* __restrict__ qkh, float* __restrict__ arow) {
    __shared__ __align__(16) u8 Sk[32768];
    const int t = threadIdx.x, w = t >> 6, l = t & 63;
    const int qt = blockIdx.x >> 1, kh = blockIdx.x & 1;
    const int h = blockIdx.y, b = blockIdx.z;
    const u8* qp = qkh + ((size_t)((b * 12 + h) * 2 + 0) << 16) + qt * 8192;
    const u8* kp = qkh + ((size_t)((b * 12 + h) * 2 + 1) << 16) + kh * 32768;

#pragma unroll
    for (int i = 0; i < 8; i++)
        gld_lds16(kp + (i * 256 + t) * 16, Sk + (i * 256 + t) * 16);

    const int ln = l & 31, lh = l >> 5;
    union F8x32 { uint4 q[2]; i32x8 v; };

    const int rA = w * 32 + ln, uA = rA >> 1, u7A = uA & 7;
    const int sA = (rA & 1) * 4 + lh * 2;
    F8x32 ua;
    ua.q[0] = *(const uint4*)(qp + uA * 128 + ((sA)     ^ u7A) * 16);
    ua.q[1] = *(const uint4*)(qp + uA * 128 + ((sA + 1) ^ u7A) * 16);

    float rs[16];
#pragma unroll
    for (int r = 0; r < 16; r++) rs[r] = 0.f;

    __builtin_amdgcn_s_waitcnt(0);
    __syncthreads();

#pragma unroll 2
    for (int nt = 0; nt < 16; nt++) {
        const int rB = nt * 32 + ln, uB = rB >> 1, u7B = uB & 7;
        const int sB = (rB & 1) * 4 + lh * 2;
        F8x32 ub;
        ub.q[0] = *(const uint4*)(Sk + uB * 128 + ((sB)     ^ u7B) * 16);
        ub.q[1] = *(const uint4*)(Sk + uB * 128 + ((sB + 1) ^ u7B) * 16);
        f32x16 acc;
#pragma unroll
        for (int q = 0; q < 16; q++) acc[q] = 0.f;
        acc = __builtin_amdgcn_mfma_scale_f32_32x32x64_f8f6f4(
            ua.v, ub.v, acc, 0, 0, 0, SCALE_A_M8, 0, SCALE_ONE);
#pragma unroll
        for (int r = 0; r < 16; r++) rs[r] += __builtin_amdgcn_exp2f(acc[r]);
    }

    const int rowbase = (b * 12 + h) * 1024 + qt * 128 + w * 32 + lh * 4;
#pragma unroll
    for (int r = 0; r < 16; r++) {
        float v = rs[r];
        v += __shfl_xor(v, 1, 32);
        v += __shfl_xor(v, 2, 32);
        v += __shfl_xor(v, 4, 32);
        v += __shfl_xor(v, 8, 32);
        v += __shfl_xor(v, 16, 32);
        if (ln == 0)
            atomicAdd(&arow[rowbase + (r & 3) + 8 * (r >> 2)], v);
    }
}

// ---------------------------------------------------------------- merged finalize
__global__ void finalize(const float* __restrict__ sums, const float* __restrict__ beta_p,
                         float* __restrict__ out) {
    __shared__ float wpart[4];
    const int t = threadIdx.x, w = t >> 6, l = t & 63;
    const int i = blockIdx.x * 256 + t;
    float v;
    if (i < 8192) v = (-1.f / beta_p[0]) * __logf(sums[i]);
    else          v = -8.f * __logf(sums[i]);
    for (int o = 32; o > 0; o >>= 1) v += __shfl_down(v, o, 64);
    if (l == 0) wpart[w] = v;
    __syncthreads();
    if (t == 0) atomicAdd(out, wpart[0] + wpart[1] + wpart[2] + wpart[3]);
}

// ---------------------------------------------------------------- launch
extern "C" void kernel_launch(void* const* d_in, const int* in_sizes, int n_in,
                              void* d_out, int out_size, void* d_ws, size_t ws_size,
                              hipStream_t stream) {
    const float* g    = (const float*)d_in[0];
    const float* wq   = (const float*)d_in[1];
    const float* wk   = (const float*)d_in[2];
    const float* w_hn = (const float*)d_in[3];
    const float* beta = (const float*)d_in[4];
    float* out = (float*)d_out;

    char* ws = (char*)d_ws;
    u8*    g_f8   = (u8*)(ws);                    //  6,291,456 B
    u8*    Wcat   = (u8*)(ws + 6291456);          //  3,538,944 B
    u8*    qkh    = (u8*)(ws + 9830400);          // 12,582,912 B [8][12][2] 64KB planes
    float* sums   = (float*)(ws + 22413312);      // rowsum 8192 | arow 98304
    float* rowsum = sums;
    float* arow   = sums + 8192;

    cast_all<<<9600, 256, 0, stream>>>(g, wq, wk, w_hn, g_f8, Wcat, sums, out);

    dim3 gg(64, 36);
    gemm_fused<<<gg, 256, 0, stream>>>(g_f8, Wcat, qkh, rowsum, beta);

    dim3 ga(16, 12, 8);   // (qt,kh), h, b
    attn_energy<<<ga, 256, 0, stream>>>(qkh, arow);

    finalize<<<416, 256, 0, stream>>>(sums, beta, out);
}

// Round 12
// 152.966 us; speedup vs baseline: 1.0530x; 1.0530x over previous
//
#include <hip/hip_runtime.h>
#include <hip/hip_bf16.h>
#include <stdint.h>
#include <stddef.h>

typedef float  f32x4  __attribute__((ext_vector_type(4)));
typedef float  f32x16 __attribute__((ext_vector_type(16)));
typedef int    i32x8  __attribute__((ext_vector_type(8)));
typedef unsigned char u8;

#define LOG2E  1.44269504f
#define QSCALE 0.18033688f      /* 0.125 * log2(e) */
#define WSC    16.0f            /* weight prescale before fp8 cast */
#define IWSC   0.0625f
#define QSTORE 0.36067376f      /* QSCALE * 32 / 16 : gemm-acc -> q_fp8 */
#define KSTORE 0.5f             /* 8 / 16          : gemm-acc -> k_fp8 */
#define SCALE_A_M8 0x77777777   /* e8m0 119 = 2^-8 (undo 32*8) */
#define SCALE_ONE  0x7F7F7F7F   /* e8m0 127 = 1.0 */

// ---------------------------------------------------------------- helpers
__device__ __forceinline__ void gld_lds16(const void* gptr, void* lptr) {
    __builtin_amdgcn_global_load_lds(
        (const __attribute__((address_space(1))) unsigned int*)gptr,
        (__attribute__((address_space(3))) unsigned int*)lptr,
        16, 0, 0);
}

// ---------------------------------------------------------------- merged cast + zero
// fp8 e4m3. blocks [0,6144): g (x1) ; [6144,6720): wq ; [6720,7296): wk ;
// [7296,9600): w_hn (weights x16). blocks [0,104) zero sums; block 0 zeroes out[0].
__global__ void cast_all(const float* __restrict__ g, const float* __restrict__ wq,
                         const float* __restrict__ wk, const float* __restrict__ whn,
                         u8* __restrict__ g_f8, u8* __restrict__ Wcat,
                         float* __restrict__ sums, float* __restrict__ out) {
    int b = blockIdx.x, t = threadIdx.x;
    if (b < 104) {
        float4 z = {0.f, 0.f, 0.f, 0.f};
        *(float4*)(sums + (b * 256 + t) * 4) = z;
        if (b == 0 && t == 0) out[0] = 0.f;
    }
    const float* src; u8* dst; int off; float sc;
    if (b < 6144)      { src = g;   dst = g_f8;           off = 0;    sc = 1.0f; }
    else if (b < 6720) { src = wq;  dst = Wcat;           off = 6144; sc = WSC;  }
    else if (b < 7296) { src = wk;  dst = Wcat + 589824;  off = 6720; sc = WSC;  }
    else               { src = whn; dst = Wcat + 1179648; off = 7296; sc = WSC;  }
    int i = ((b - off) * 256 + t) * 4;
    float4 v = *(const float4*)(src + i);
    int p = __builtin_amdgcn_cvt_pk_fp8_f32(sc * v.x, sc * v.y, 0, false);
    p     = __builtin_amdgcn_cvt_pk_fp8_f32(sc * v.z, sc * v.w, p, true);
    *(int*)(dst + i) = p;
}

// ---------------------------------------------------------------- fused NT GEMM (MX-fp8)
// C_full[M,4608] = A[M,768] * Wcat[4608,768]^T, fp8 e4m3, fp32 acc.
// R12: R10's verified 2-barrier BK=128 structure (44.4 us best), but the inner
// product uses 2 k-steps x 4 x mfma_scale_f32_32x32x64 (8 MFMA/iter) instead of
// 16 x 16x16x128 — same FLOPs, same 16 ds_read_b128, HALF the MFMA issue count.
// (R11's fine-grained BK=64 pipeline regressed 59us: 4-MFMA stages can't cover
// ~500cy load latency; drains doubled. Reverted.)
// LDS [row][seg16] with XOR swizzle: slot s holds global seg s^(row&7).
// cols [0,1536): q/k -> fp8 qkh planes (super-row swizzle), q*QSTORE, k*KSTORE.
// cols [1536,4608): Hopfield -> rowsum += exp2(beta*log2e/16 * acc) via atomicAdd.
__global__ void gemm_fused(const u8* __restrict__ A, const u8* __restrict__ Bm,
                           u8* __restrict__ qkh, float* __restrict__ rowsum,
                           const float* __restrict__ beta_p) {
    __shared__ __align__(16) u8 As[128 * 128];
    __shared__ __align__(16) u8 Bs[128 * 128];
    const int t = threadIdx.x;
    const int w = t >> 6, l = t & 63;
    const int wm = (w >> 1) * 64, wn = (w & 1) * 64;
    const int tile_m = blockIdx.x * 128;
    const int tile_n = blockIdx.y * 128;

    f32x16 acc[2][2];
#pragma unroll
    for (int i = 0; i < 2; i++)
#pragma unroll
        for (int j = 0; j < 2; j++)
#pragma unroll
            for (int q = 0; q < 16; q++) acc[i][j][q] = 0.f;

    const int srow = t >> 3;
    const int sswz = (t & 7) ^ (srow & 7);
    const u8* gA = A  + (size_t)(tile_m + srow) * 768 + sswz * 16;
    const u8* gB = Bm + (size_t)(tile_n + srow) * 768 + sswz * 16;

    const int ln = l & 31, lh = l >> 5;
    union F8x32 { uint4 q[2]; i32x8 v; };

    for (int k0 = 0; k0 < 768; k0 += 128) {
#pragma unroll
        for (int i = 0; i < 4; i++) {
            gld_lds16(gA + (size_t)i * 32 * 768 + k0, As + (i * 256 + t) * 16);
            gld_lds16(gB + (size_t)i * 32 * 768 + k0, Bs + (i * 256 + t) * 16);
        }
        __builtin_amdgcn_s_waitcnt(0);
        __syncthreads();

#pragma unroll
        for (int ks = 0; ks < 2; ks++) {
            const int s = ks * 4 + lh * 2;   // global seg pair {s, s+1} (32 k-bytes)
            i32x8 af[2], bf[2];
#pragma unroll
            for (int mi = 0; mi < 2; mi++) {
                int rA = wm + mi * 32 + ln, r7 = rA & 7;
                F8x32 x;
                x.q[0] = *(const uint4*)(As + rA * 128 + ((s)     ^ r7) * 16);
                x.q[1] = *(const uint4*)(As + rA * 128 + ((s + 1) ^ r7) * 16);
                af[mi] = x.v;
                int rB = wn + mi * 32 + ln, b7 = rB & 7;
                F8x32 y;
                y.q[0] = *(const uint4*)(Bs + rB * 128 + ((s)     ^ b7) * 16);
                y.q[1] = *(const uint4*)(Bs + rB * 128 + ((s + 1) ^ b7) * 16);
                bf[mi] = y.v;
            }
#pragma unroll
            for (int mi = 0; mi < 2; mi++)
#pragma unroll
                for (int nj = 0; nj < 2; nj++)
                    acc[mi][nj] = __builtin_amdgcn_mfma_scale_f32_32x32x64_f8f6f4(
                        af[mi], bf[nj], acc[mi][nj], 0, 0, 0, SCALE_ONE, 0, SCALE_ONE);
        }
        __syncthreads();
    }

    // C/D layout (32x32, m74/m101-verified, R11-validated): col=lane&31,
    // row=(r&3)+8*(r>>2)+4*lh
    if (tile_n < 1536) {
        const int tt = (tile_n >= 768);
        const int bb = tile_m >> 10;
        const int m7 = tile_m & 1023;
        const float sc = tt ? KSTORE : QSTORE;
#pragma unroll
        for (int mi = 0; mi < 2; mi++)
#pragma unroll
            for (int nj = 0; nj < 2; nj++) {
                const int colbase = tile_n - tt * 768 + wn + nj * 32;  // 0..767
                const int hh = colbase >> 6;
                const int z  = (colbase & 63) + ln;                    // 0..63
                u8* base = qkh + ((size_t)((bb * 12 + hh) * 2 + tt) << 16);
#pragma unroll
                for (int r = 0; r < 16; r++) {
                    int kr = m7 + wm + mi * 32 + (r & 3) + 8 * (r >> 2) + 4 * lh;
                    int u = kr >> 1, u7 = u & 7;
                    int slot = ((kr & 1) * 4 + (z >> 4)) ^ u7;
                    int pv = __builtin_amdgcn_cvt_pk_fp8_f32(sc * acc[mi][nj][r], 0.f, 0, false);
                    base[(size_t)u * 128 + slot * 16 + (z & 15)] = (u8)(pv & 0xFF);
                }
            }
    } else {
        const float sc2 = beta_p[0] * LOG2E * IWSC;
#pragma unroll
        for (int mi = 0; mi < 2; mi++)
#pragma unroll
            for (int r = 0; r < 16; r++) {
                float s = __builtin_amdgcn_exp2f(sc2 * acc[mi][0][r])
                        + __builtin_amdgcn_exp2f(sc2 * acc[mi][1][r]);
                s += __shfl_xor(s, 1, 32);
                s += __shfl_xor(s, 2, 32);
                s += __shfl_xor(s, 4, 32);
                s += __shfl_xor(s, 8, 32);
                s += __shfl_xor(s, 16, 32);
                if (ln == 0)
                    atomicAdd(&rowsum[tile_m + wm + mi * 32 + (r & 3) + 8 * (r >> 2) + 4 * lh], s);
            }
    }
}

// ---------------------------------------------------------------- attention exp-sums
// qkh fp8 planes (super-row swizzled). grid (qt*2+kh:16, h:12, b:8), 256 thr.
// All 512 K-rows staged once (32 KB LDS, one drain+barrier); Q frags direct
// global->VGPR; mfma_scale_f32_32x32x64_f8f6f4 with scale_a = 2^-8 folding all
// gains: acc = beta*log2e*(q.k) -> rs += exp2(acc).
__global__ void __launch_bounds__(256, 4)
attn_energy(const u8* __restrict__ qkh, float* __restrict__ arow) {
    __shared__ __align__(16) u8 Sk[32768];
    const int t = threadIdx.x, w = t >> 6, l = t & 63;
    const int qt = blockIdx.x >> 1, kh = blockIdx.x & 1;
    const int h = blockIdx.y, b = blockIdx.z;
    const u8* qp = qkh + ((size_t)((b * 12 + h) * 2 + 0) << 16) + qt * 8192;
    const u8* kp = qkh + ((size_t)((b * 12 + h) * 2 + 1) << 16) + kh * 32768;

#pragma unroll
    for (int i = 0; i < 8; i++)
        gld_lds16(kp + (i * 256 + t) * 16, Sk + (i * 256 + t) * 16);

    const int ln = l & 31, lh = l >> 5;
    union F8x32 { uint4 q[2]; i32x8 v; };

    const int rA = w * 32 + ln, uA = rA >> 1, u7A = uA & 7;
    const int sA = (rA & 1) * 4 + lh * 2;
    F8x32 ua;
    ua.q[0] = *(const uint4*)(qp + uA * 128 + ((sA)     ^ u7A) * 16);
    ua.q[1] = *(const uint4*)(qp + uA * 128 + ((sA + 1) ^ u7A) * 16);

    float rs[16];
#pragma unroll
    for (int r = 0; r < 16; r++) rs[r] = 0.f;

    __builtin_amdgcn_s_waitcnt(0);
    __syncthreads();

#pragma unroll 2
    for (int nt = 0; nt < 16; nt++) {
        const int rB = nt * 32 + ln, uB = rB >> 1, u7B = uB & 7;
        const int sB = (rB & 1) * 4 + lh * 2;
        F8x32 ub;
        ub.q[0] = *(const uint4*)(Sk + uB * 128 + ((sB)     ^ u7B) * 16);
        ub.q[1] = *(const uint4*)(Sk + uB * 128 + ((sB + 1) ^ u7B) * 16);
        f32x16 acc;
#pragma unroll
        for (int q = 0; q < 16; q++) acc[q] = 0.f;
        acc = __builtin_amdgcn_mfma_scale_f32_32x32x64_f8f6f4(
            ua.v, ub.v, acc, 0, 0, 0, SCALE_A_M8, 0, SCALE_ONE);
#pragma unroll
        for (int r = 0; r < 16; r++) rs[r] += __builtin_amdgcn_exp2f(acc[r]);
    }

    const int rowbase = (b * 12 + h) * 1024 + qt * 128 + w * 32 + lh * 4;
#pragma unroll
    for (int r = 0; r < 16; r++) {
        float v = rs[r];
        v += __shfl_xor(v, 1, 32);
        v += __shfl_xor(v, 2, 32);
        v += __shfl_xor(v, 4, 32);
        v += __shfl_xor(v, 8, 32);
        v += __shfl_xor(v, 16, 32);
        if (ln == 0)
            atomicAdd(&arow[rowbase + (r & 3) + 8 * (r >> 2)], v);
    }
}

// ---------------------------------------------------------------- merged finalize
__global__ void finalize(const float* __restrict__ sums, const float* __restrict__ beta_p,
                         float* __restrict__ out) {
    __shared__ float wpart[4];
    const int t = threadIdx.x, w = t >> 6, l = t & 63;
    const int i = blockIdx.x * 256 + t;
    float v;
    if (i < 8192) v = (-1.f / beta_p[0]) * __logf(sums[i]);
    else          v = -8.f * __logf(sums[i]);
    for (int o = 32; o > 0; o >>= 1) v += __shfl_down(v, o, 64);
    if (l == 0) wpart[w] = v;
    __syncthreads();
    if (t == 0) atomicAdd(out, wpart[0] + wpart[1] + wpart[2] + wpart[3]);
}

// ---------------------------------------------------------------- launch
extern "C" void kernel_launch(void* const* d_in, const int* in_sizes, int n_in,
                              void* d_out, int out_size, void* d_ws, size_t ws_size,
                              hipStream_t stream) {
    const float* g    = (const float*)d_in[0];
    const float* wq   = (const float*)d_in[1];
    const float* wk   = (const float*)d_in[2];
    const float* w_hn = (const float*)d_in[3];
    const float* beta = (const float*)d_in[4];
    float* out = (float*)d_out;

    char* ws = (char*)d_ws;
    u8*    g_f8   = (u8*)(ws);                    //  6,291,456 B
    u8*    Wcat   = (u8*)(ws + 6291456);          //  3,538,944 B
    u8*    qkh    = (u8*)(ws + 9830400);          // 12,582,912 B [8][12][2] 64KB planes
    float* sums   = (float*)(ws + 22413312);      // rowsum 8192 | arow 98304
    float* rowsum = sums;
    float* arow   = sums + 8192;

    cast_all<<<9600, 256, 0, stream>>>(g, wq, wk, w_hn, g_f8, Wcat, sums, out);

    dim3 gg(64, 36);
    gemm_fused<<<gg, 256, 0, stream>>>(g_f8, Wcat, qkh, rowsum, beta);

    dim3 ga(16, 12, 8);   // (qt,kh), h, b
    attn_energy<<<ga, 256, 0, stream>>>(qkh, arow);

    finalize<<<416, 256, 0, stream>>>(sums, beta, out);
}

// Round 13
// 146.382 us; speedup vs baseline: 1.1004x; 1.0450x over previous
//
#include <hip/hip_runtime.h>
#include <hip/hip_bf16.h>
#include <stdint.h>
#include <stddef.h>

typedef float  f32x4  __attribute__((ext_vector_type(4)));
typedef float  f32x16 __attribute__((ext_vector_type(16)));
typedef int    i32x8  __attribute__((ext_vector_type(8)));
typedef unsigned char u8;

#define LOG2E  1.44269504f
#define QSCALE 0.18033688f      /* 0.125 * log2(e) */
#define WSC    16.0f            /* weight prescale before fp8 cast */
#define IWSC   0.0625f
#define QSTORE 0.36067376f      /* QSCALE * 32 / 16 : gemm-acc -> q_fp8 */
#define KSTORE 0.5f             /* 8 / 16          : gemm-acc -> k_fp8 */
#define SCALE_A_M8 0x77777777   /* e8m0 119 = 2^-8 (undo 32*8) */
#define SCALE_ONE  0x7F7F7F7F   /* e8m0 127 = 1.0 */

// ---------------------------------------------------------------- helpers
__device__ __forceinline__ void gld_lds16(const void* gptr, void* lptr) {
    __builtin_amdgcn_global_load_lds(
        (const __attribute__((address_space(1))) unsigned int*)gptr,
        (__attribute__((address_space(3))) unsigned int*)lptr,
        16, 0, 0);
}

// ---------------------------------------------------------------- merged cast + zero
// fp8 e4m3. blocks [0,6144): g (x1) ; [6144,6720): wq ; [6720,7296): wk ;
// [7296,9600): w_hn (weights x16). blocks [0,104) zero sums; block 0 zeroes out[0].
__global__ void cast_all(const float* __restrict__ g, const float* __restrict__ wq,
                         const float* __restrict__ wk, const float* __restrict__ whn,
                         u8* __restrict__ g_f8, u8* __restrict__ Wcat,
                         float* __restrict__ sums, float* __restrict__ out) {
    int b = blockIdx.x, t = threadIdx.x;
    if (b < 104) {
        float4 z = {0.f, 0.f, 0.f, 0.f};
        *(float4*)(sums + (b * 256 + t) * 4) = z;
        if (b == 0 && t == 0) out[0] = 0.f;
    }
    const float* src; u8* dst; int off; float sc;
    if (b < 6144)      { src = g;   dst = g_f8;           off = 0;    sc = 1.0f; }
    else if (b < 6720) { src = wq;  dst = Wcat;           off = 6144; sc = WSC;  }
    else if (b < 7296) { src = wk;  dst = Wcat + 589824;  off = 6720; sc = WSC;  }
    else               { src = whn; dst = Wcat + 1179648; off = 7296; sc = WSC;  }
    int i = ((b - off) * 256 + t) * 4;
    float4 v = *(const float4*)(src + i);
    int p = __builtin_amdgcn_cvt_pk_fp8_f32(sc * v.x, sc * v.y, 0, false);
    p     = __builtin_amdgcn_cvt_pk_fp8_f32(sc * v.z, sc * v.w, p, true);
    *(int*)(dst + i) = p;
}

// ---------------------------------------------------------------- fused NT GEMM (MX-fp8)
// R13: VERBATIM REVERT to the R10/R9 configuration — best measured (44.4 us).
// Both structural neighbors measured worse: R11 BK=64 dbuf pipeline 59 us
// (4-MFMA stages can't cover ~500cy load latency); R12 32x32x64 retile 48.4 us
// (2-deep acc chains hide MFMA latency worse than 16x16x128's 4-deep).
// C_full[M,4608] = A[M,768] * Wcat[4608,768]^T, fp8 e4m3, fp32 acc.
// mfma_scale_f32_16x16x128_f8f6f4, unit scales. BM=BN=128, BK=128.
// LDS [row][seg16] XOR swizzle: slot s holds global seg s^(row&7).
// cols [0,1536): q/k -> fp8 qkh planes (1024x64 B), SUPER-ROW swizzle:
//   u=kr>>1, slot=((kr&1)*4+(z>>4))^(u&7), byte z&15. q*QSTORE, k*KSTORE.
// cols [1536,4608): Hopfield -> rowsum += exp2(beta*log2e/16 * acc) via atomicAdd.
__global__ void gemm_fused(const u8* __restrict__ A, const u8* __restrict__ Bm,
                           u8* __restrict__ qkh, float* __restrict__ rowsum,
                           const float* __restrict__ beta_p) {
    __shared__ __align__(16) u8 As[128 * 128];
    __shared__ __align__(16) u8 Bs[128 * 128];
    const int t = threadIdx.x;
    const int w = t >> 6, l = t & 63;
    const int wm = (w >> 1) * 64, wn = (w & 1) * 64;
    const int tile_m = blockIdx.x * 128;
    const int tile_n = blockIdx.y * 128;

    f32x4 acc[4][4];
#pragma unroll
    for (int i = 0; i < 4; i++)
#pragma unroll
        for (int j = 0; j < 4; j++)
#pragma unroll
            for (int q = 0; q < 4; q++) acc[i][j][q] = 0.f;

    const int srow = t >> 3;
    const int sswz = (t & 7) ^ (srow & 7);
    const u8* gA = A  + (size_t)(tile_m + srow) * 768 + sswz * 16;
    const u8* gB = Bm + (size_t)(tile_n + srow) * 768 + sswz * 16;

    const int fr = l & 15, fg = l >> 4;
    const int s0 = ((2 * fg)     ^ (fr & 7)) * 16;
    const int s1 = ((2 * fg + 1) ^ (fr & 7)) * 16;

    for (int k0 = 0; k0 < 768; k0 += 128) {
#pragma unroll
        for (int i = 0; i < 4; i++) {
            gld_lds16(gA + (size_t)i * 32 * 768 + k0, As + (i * 256 + t) * 16);
            gld_lds16(gB + (size_t)i * 32 * 768 + k0, Bs + (i * 256 + t) * 16);
        }
        __builtin_amdgcn_s_waitcnt(0);
        __syncthreads();

        union F8 { uint4 q[2]; i32x8 v; };
        i32x8 af[4], bfr[4];
#pragma unroll
        for (int i = 0; i < 4; i++) {
            const u8* ra = As + (wm + i * 16 + fr) * 128;
            const u8* rb = Bs + (wn + i * 16 + fr) * 128;
            F8 ua, ub;
            ua.q[0] = *(const uint4*)(ra + s0);
            ua.q[1] = *(const uint4*)(ra + s1);
            ub.q[0] = *(const uint4*)(rb + s0);
            ub.q[1] = *(const uint4*)(rb + s1);
            af[i] = ua.v; bfr[i] = ub.v;
        }
#pragma unroll
        for (int i = 0; i < 4; i++)
#pragma unroll
            for (int j = 0; j < 4; j++)
                acc[i][j] = __builtin_amdgcn_mfma_scale_f32_16x16x128_f8f6f4(
                    af[i], bfr[j], acc[i][j], 0, 0, 0, SCALE_ONE, 0, SCALE_ONE);
        __syncthreads();
    }

    const int cr = fg * 4, cc = fr;

    if (tile_n < 1536) {
        const int tt = (tile_n >= 768);
        const int hh = (tile_n - tt * 768 + wn) >> 6;
        const int bb = tile_m >> 10;
        const int m7 = tile_m & 1023;
        const float sc = tt ? KSTORE : QSTORE;
        u8* base = qkh + ((size_t)((bb * 12 + hh) * 2 + tt) << 16);
#pragma unroll
        for (int i = 0; i < 4; i++)
#pragma unroll
            for (int r = 0; r < 4; r++) {
                int kr = m7 + wm + i * 16 + cr + r;
                int u = kr >> 1, p4 = (kr & 1) * 4, u7 = u & 7;
                u8* rowp = base + (size_t)u * 128;
#pragma unroll
                for (int j = 0; j < 4; j++) {
                    int pv = __builtin_amdgcn_cvt_pk_fp8_f32(sc * acc[i][j][r], 0.f, 0, false);
                    rowp[((p4 + j) ^ u7) * 16 + cc] = (u8)(pv & 0xFF);
                }
            }
    } else {
        const float sc2 = beta_p[0] * LOG2E * IWSC;
#pragma unroll
        for (int i = 0; i < 4; i++)
#pragma unroll
            for (int r = 0; r < 4; r++) {
                float s = 0.f;
#pragma unroll
                for (int j = 0; j < 4; j++) s += __builtin_amdgcn_exp2f(sc2 * acc[i][j][r]);
                s += __shfl_xor(s, 1, 16);
                s += __shfl_xor(s, 2, 16);
                s += __shfl_xor(s, 4, 16);
                s += __shfl_xor(s, 8, 16);
                if ((l & 15) == 0)
                    atomicAdd(&rowsum[tile_m + wm + i * 16 + cr + r], s);
            }
    }
}

// ---------------------------------------------------------------- attention exp-sums
// qkh fp8 planes (super-row swizzled). grid (qt*2+kh:16, h:12, b:8), 256 thr.
// All 512 K-rows staged once (32 KB LDS, one drain+barrier); Q frags direct
// global->VGPR; mfma_scale_f32_32x32x64_f8f6f4 with scale_a = 2^-8 folding all
// gains: acc = beta*log2e*(q.k) -> rs += exp2(acc).
__global__ void __launch_bounds__(256, 4)
attn_energy(const u8* __restrict__ qkh, float* __restrict__ arow) {
    __shared__ __align__(16) u8 Sk[32768];
    const int t = threadIdx.x, w = t >> 6, l = t & 63;
    const int qt = blockIdx.x >> 1, kh = blockIdx.x & 1;
    const int h = blockIdx.y, b = blockIdx.z;
    const u8* qp = qkh + ((size_t)((b * 12 + h) * 2 + 0) << 16) + qt * 8192;
    const u8* kp = qkh + ((size_t)((b * 12 + h) * 2 + 1) << 16) + kh * 32768;

#pragma unroll
    for (int i = 0; i < 8; i++)
        gld_lds16(kp + (i * 256 + t) * 16, Sk + (i * 256 + t) * 16);

    const int ln = l & 31, lh = l >> 5;
    union F8x32 { uint4 q[2]; i32x8 v; };

    const int rA = w * 32 + ln, uA = rA >> 1, u7A = uA & 7;
    const int sA = (rA & 1) * 4 + lh * 2;
    F8x32 ua;
    ua.q[0] = *(const uint4*)(qp + uA * 128 + ((sA)     ^ u7A) * 16);
    ua.q[1] = *(const uint4*)(qp + uA * 128 + ((sA + 1) ^ u7A) * 16);

    float rs[16];
#pragma unroll
    for (int r = 0; r < 16; r++) rs[r] = 0.f;

    __builtin_amdgcn_s_waitcnt(0);
    __syncthreads();

#pragma unroll 2
    for (int nt = 0; nt < 16; nt++) {
        const int rB = nt * 32 + ln, uB = rB >> 1, u7B = uB & 7;
        const int sB = (rB & 1) * 4 + lh * 2;
        F8x32 ub;
        ub.q[0] = *(const uint4*)(Sk + uB * 128 + ((sB)     ^ u7B) * 16);
        ub.q[1] = *(const uint4*)(Sk + uB * 128 + ((sB + 1) ^ u7B) * 16);
        f32x16 acc;
#pragma unroll
        for (int q = 0; q < 16; q++) acc[q] = 0.f;
        acc = __builtin_amdgcn_mfma_scale_f32_32x32x64_f8f6f4(
            ua.v, ub.v, acc, 0, 0, 0, SCALE_A_M8, 0, SCALE_ONE);
#pragma unroll
        for (int r = 0; r < 16; r++) rs[r] += __builtin_amdgcn_exp2f(acc[r]);
    }

    const int rowbase = (b * 12 + h) * 1024 + qt * 128 + w * 32 + lh * 4;
#pragma unroll
    for (int r = 0; r < 16; r++) {
        float v = rs[r];
        v += __shfl_xor(v, 1, 32);
        v += __shfl_xor(v, 2, 32);
        v += __shfl_xor(v, 4, 32);
        v += __shfl_xor(v, 8, 32);
        v += __shfl_xor(v, 16, 32);
        if (ln == 0)
            atomicAdd(&arow[rowbase + (r & 3) + 8 * (r >> 2)], v);
    }
}

// ---------------------------------------------------------------- merged finalize
__global__ void finalize(const float* __restrict__ sums, const float* __restrict__ beta_p,
                         float* __restrict__ out) {
    __shared__ float wpart[4];
    const int t = threadIdx.x, w = t >> 6, l = t & 63;
    const int i = blockIdx.x * 256 + t;
    float v;
    if (i < 8192) v = (-1.f / beta_p[0]) * __logf(sums[i]);
    else          v = -8.f * __logf(sums[i]);
    for (int o = 32; o > 0; o >>= 1) v += __shfl_down(v, o, 64);
    if (l == 0) wpart[w] = v;
    __syncthreads();
    if (t == 0) atomicAdd(out, wpart[0] + wpart[1] + wpart[2] + wpart[3]);
}

// ---------------------------------------------------------------- launch
extern "C" void kernel_launch(void* const* d_in, const int* in_sizes, int n_in,
                              void* d_out, int out_size, void* d_ws, size_t ws_size,
                              hipStream_t stream) {
    const float* g    = (const float*)d_in[0];
    const float* wq   = (const float*)d_in[1];
    const float* wk   = (const float*)d_in[2];
    const float* w_hn = (const float*)d_in[3];
    const float* beta = (const float*)d_in[4];
    float* out = (float*)d_out;

    char* ws = (char*)d_ws;
    u8*    g_f8   = (u8*)(ws);                    //  6,291,456 B
    u8*    Wcat   = (u8*)(ws + 6291456);          //  3,538,944 B
    u8*    qkh    = (u8*)(ws + 9830400);          // 12,582,912 B [8][12][2] 64KB planes
    float* sums   = (float*)(ws + 22413312);      // rowsum 8192 | arow 98304
    float* rowsum = sums;
    float* arow   = sums + 8192;

    cast_all<<<9600, 256, 0, stream>>>(g, wq, wk, w_hn, g_f8, Wcat, sums, out);

    dim3 gg(64, 36);
    gemm_fused<<<gg, 256, 0, stream>>>(g_f8, Wcat, qkh, rowsum, beta);

    dim3 ga(16, 12, 8);   // (qt,kh), h, b
    attn_energy<<<ga, 256, 0, stream>>>(qkh, arow);

    finalize<<<416, 256, 0, stream>>>(sums, beta, out);
}